// Round 4
// baseline (666.821 us; speedup 1.0000x reference)
//
#include <hip/hip_runtime.h>
#include <math.h>

namespace {
constexpr int N_ = 16, L_ = 256, S_ = 128, E_ = 128, A_ = 9, D_ = 768, H_ = 768, RO_ = 24;
constexpr int IDXW = 130;       // S+2
constexpr int W1R = 6 * D_;     // 4608
constexpr float INV_SQRT_D = 0.03608439182435161f; // 1/sqrt(768)
constexpr int PESZ = 2048 * 768;   // one Pe partial
constexpr int PASZ = 144 * 768;    // one Pa partial
// phase-1 chunk ranges (longest work first)
constexpr int GB_T2T    = 0;       // 1024 (16 n x 64 s-pairs)
constexpr int GB_W1T    = 1024;    // 864  (72 k-tiles x 12 h-tiles)
constexpr int GB_GATHER = 1888;    // 192  (16 n x 12 d-tiles)
constexpr int GB_ENTMAP = 2080;    // 16
constexpr int GB_ARGU   = 2096;    // 16
constexpr int GB_TOTAL  = 2112;
} // namespace

using bshort8 = __attribute__((ext_vector_type(8))) short;
using f32x4v = __attribute__((ext_vector_type(4))) float;

__device__ __forceinline__ unsigned short f2bf(float f) {
    unsigned u = __builtin_bit_cast(unsigned, f);
    return (unsigned short)((u + 0x7fffu + ((u >> 16) & 1u)) >> 16);
}

// device-scope grid barrier (all blocks resident by construction of grid size)
__device__ __forceinline__ void gbar(unsigned* bar) {
    __syncthreads();
    if (threadIdx.x == 0) {
        __threadfence();   // release prior writes to agent scope
        const unsigned g = __hip_atomic_load(&bar[1], __ATOMIC_RELAXED, __HIP_MEMORY_SCOPE_AGENT);
        const unsigned a = __hip_atomic_fetch_add(&bar[0], 1u, __ATOMIC_ACQ_REL, __HIP_MEMORY_SCOPE_AGENT);
        if (a == gridDim.x - 1) {
            __hip_atomic_store(&bar[0], 0u, __ATOMIC_RELAXED, __HIP_MEMORY_SCOPE_AGENT);
            __hip_atomic_fetch_add(&bar[1], 1u, __ATOMIC_RELEASE, __HIP_MEMORY_SCOPE_AGENT);
        } else {
            unsigned spins = 0;
            while (__hip_atomic_load(&bar[1], __ATOMIC_ACQUIRE, __HIP_MEMORY_SCOPE_AGENT) == g) {
                if (++spins > 0x40000000u) break;  // safety valve: garbage beats hang
            }
        }
        __threadfence();   // acquire side
    }
    __syncthreads();
}

// shared 128x64-tile K=128 GEMM body: acc += A(128x128) @ B(128x64 from BT[col][k])
__device__ __forceinline__ void gemm_body128(const unsigned short* __restrict__ A,
                                             const unsigned short* __restrict__ BT,
                                             int lda, int ldb, int c0, int tid,
                                             short (*As)[40], short (*Bs)[40],
                                             f32x4v acc[2][4]) {
    const int wave = tid >> 6, lane = tid & 63;
    const int row16 = lane & 15, quad = lane >> 4;
    for (int k0 = 0; k0 < S_; k0 += 32) {
#pragma unroll
        for (int i = 0; i < 2; ++i) {
            const int idx = tid + 256 * i;
            const int r = idx >> 2, q = idx & 3;
            *reinterpret_cast<bshort8*>(&As[r][q * 8]) =
                *reinterpret_cast<const bshort8*>(A + (size_t)r * lda + k0 + q * 8);
        }
        {
            const int col = tid >> 2, q = tid & 3;
            *reinterpret_cast<bshort8*>(&Bs[col][q * 8]) =
                *reinterpret_cast<const bshort8*>(BT + (size_t)(c0 + col) * ldb + k0 + q * 8);
        }
        __syncthreads();
        bshort8 a[2], b[4];
#pragma unroll
        for (int mi = 0; mi < 2; ++mi)
            a[mi] = *reinterpret_cast<const bshort8*>(&As[wave * 32 + mi * 16 + row16][quad * 8]);
#pragma unroll
        for (int ni = 0; ni < 4; ++ni)
            b[ni] = *reinterpret_cast<const bshort8*>(&Bs[ni * 16 + row16][quad * 8]);
#pragma unroll
        for (int mi = 0; mi < 2; ++mi)
#pragma unroll
            for (int ni = 0; ni < 4; ++ni)
                acc[mi][ni] = __builtin_amdgcn_mfma_f32_16x16x32_bf16(a[mi], b[ni], acc[mi][ni], 0, 0, 0);
        __syncthreads();
    }
}

// ======== the whole pipeline in one resident kernel, 6 phases / 5 grid barriers ========
__global__ __launch_bounds__(256) void mega_k(
    const float* __restrict__ all_emb, const float* __restrict__ attn,
    const float* __restrict__ ent_map, const float* __restrict__ argw,
    const float* __restrict__ W1, const float* __restrict__ b1,
    const float* __restrict__ W2, const float* __restrict__ b2,
    const int* __restrict__ idxs, const int* __restrict__ arg_map,
    float* __restrict__ out,
    float* __restrict__ entf, float* __restrict__ Pe3, float* __restrict__ argE,
    float* __restrict__ Pa3, float* __restrict__ wbuf,
    short* __restrict__ W1t,
    unsigned short* __restrict__ sentT, unsigned short* __restrict__ entmapT,
    unsigned short* __restrict__ t2tT, unsigned short* __restrict__ M1bf,
    unsigned short* __restrict__ argEbf, unsigned short* __restrict__ u2ubf,
    unsigned short* __restrict__ entbf, unsigned short* __restrict__ Ah2hbf,
    unsigned short* __restrict__ tokAbf, unsigned short* __restrict__ argTbf,
    unsigned* bar) {
    __shared__ __align__(16) unsigned char smem[33792];
    const int G = gridDim.x, tid = threadIdx.x;

    // ---------------- phase 1: input-only transforms (2112 chunks) ----------------
    for (int b = blockIdx.x; b < GB_TOTAL; b += G) {
        if (b < GB_W1T) {
            // t2t: two s-rows per chunk; output TRANSPOSED t2tT[n][t][s]
            const int idx = b - GB_T2T;
            const int n = idx >> 6;
            const int half = tid >> 7, t128 = tid & 127;
            const int s0 = (idx & 63) << 1;
            const int s = s0 | half;
            const int w = t128 >> 6, lane = tid & 63;
            float* sum2 = (float*)smem;                       // [2][3][2][256] = 12288B
            float* part = (float*)(smem + 12288);             // 12 floats
            unsigned short* tileT = (unsigned short*)(smem + 12544); // [128][2]
            const int is = idxs[n * IDXW + s], it = idxs[n * IDXW + t128];
#pragma unroll
            for (int l = 0; l < 3; ++l) {
                const float* base = attn + ((size_t)((l * N_ + n) * 12 + w * 6)) * (L_ * L_)
                                  + (size_t)is * L_ + lane * 4;
                float4 acc = {0.f, 0.f, 0.f, 0.f};
#pragma unroll
                for (int h = 0; h < 6; ++h) {
                    const float4 v = *reinterpret_cast<const float4*>(base + (size_t)h * (L_ * L_));
                    acc.x += v.x; acc.y += v.y; acc.z += v.z; acc.w += v.w;
                }
                *reinterpret_cast<float4*>(&sum2[(((half * 3 + l) * 2 + w) << 8) + lane * 4]) = acc;
            }
            __syncthreads();
            float m[3];
#pragma unroll
            for (int l = 0; l < 3; ++l) {
                m[l] = (sum2[(((half * 3 + l) * 2 + 0) << 8) + it] +
                        sum2[(((half * 3 + l) * 2 + 1) << 8) + it]) * (1.0f / 12.0f);
                float r = m[l];
#pragma unroll
                for (int off = 32; off; off >>= 1) r += __shfl_xor(r, off, 64);
                if (lane == 0) part[(half * 3 + l) * 2 + w] = r;
            }
            __syncthreads();
            float o = 0.f;
#pragma unroll
            for (int l = 0; l < 3; ++l)
                o += m[l] / (part[(half * 3 + l) * 2 + 0] + part[(half * 3 + l) * 2 + 1] + 1e-9f);
            tileT[t128 * 2 + half] = f2bf(o * (1.0f / 3.0f));
            __syncthreads();
            if (tid < 128) {
                const unsigned int v = ((const unsigned int*)tileT)[tid];
                *reinterpret_cast<unsigned int*>(t2tT + ((size_t)(n * S_) + tid) * S_ + s0) = v;
            }
        } else if (b < GB_GATHER) {
            // W1t[h][k] = bf16(W1[k][h])
            const int b2 = b - GB_W1T;
            const int k0 = (b2 % 72) * 64, h0 = (b2 / 72) * 64;
            auto tile = (float (*)[65])smem;
            const int tx = tid & 63, ty = tid >> 6;
#pragma unroll
            for (int i = 0; i < 16; ++i) {
                const int r = ty + i * 4;
                tile[r][tx] = W1[(size_t)(k0 + r) * H_ + h0 + tx];
            }
            __syncthreads();
#pragma unroll
            for (int i = 0; i < 16; ++i) {
                const int r = ty + i * 4;
                W1t[(size_t)(h0 + r) * W1R + k0 + tx] = (short)f2bf(tile[tx][r]);
            }
        } else if (b < GB_ENTMAP) {
            // gatherT: sentT[n][d][s] = bf16(all_emb[n][idx[s]][d])
            const int b2 = b - GB_GATHER;
            const int n = b2 / 12, d0 = (b2 % 12) * 64;
            auto tile = (unsigned short (*)[132])smem;
#pragma unroll
            for (int it = 0; it < 8; ++it) {
                const int lin = tid + 256 * it;
                const int s = lin >> 4, dq = (lin & 15) * 4;
                const int row = idxs[n * IDXW + s];
                const float4 v = *reinterpret_cast<const float4*>(all_emb + ((size_t)(n * L_ + row)) * D_ + d0 + dq);
                tile[dq + 0][s] = f2bf(v.x); tile[dq + 1][s] = f2bf(v.y);
                tile[dq + 2][s] = f2bf(v.z); tile[dq + 3][s] = f2bf(v.w);
            }
            __syncthreads();
#pragma unroll
            for (int it = 0; it < 8; ++it) {
                const int lin = tid + 256 * it;
                const int d = lin >> 5, s4 = (lin & 31) * 4;
                ushort4 v = {tile[d][s4], tile[d][s4 + 1], tile[d][s4 + 2], tile[d][s4 + 3]};
                *reinterpret_cast<ushort4*>(sentT + ((size_t)(n * D_) + d0 + d) * S_ + s4) = v;
            }
        } else if (b < GB_ARGU) {
            // entmapT[n][e][s] = bf16(ent_map[n][s][e])
            const int n = b - GB_ENTMAP;
            auto tile = (unsigned short (*)[132])smem;
#pragma unroll
            for (int it = 0; it < 16; ++it) {
                const int lin = tid + 256 * it;
                const int s = lin >> 5, eq = (lin & 31) * 4;
                const float4 v = *reinterpret_cast<const float4*>(ent_map + ((size_t)(n * S_ + s)) * E_ + eq);
                tile[eq + 0][s] = f2bf(v.x); tile[eq + 1][s] = f2bf(v.y);
                tile[eq + 2][s] = f2bf(v.z); tile[eq + 3][s] = f2bf(v.w);
            }
            __syncthreads();
#pragma unroll
            for (int it = 0; it < 16; ++it) {
                const int lin = tid + 256 * it;
                const int e = lin >> 5, s4 = (lin & 31) * 4;
                ushort4 v = {tile[e][s4], tile[e][s4 + 1], tile[e][s4 + 2], tile[e][s4 + 3]};
                *reinterpret_cast<ushort4*>(entmapT + ((size_t)(n * E_) + e) * S_ + s4) = v;
            }
        } else {
            // arg_u2u: arg_emb + a2a softmax + u2u
            const int n = b - GB_ARGU;
            auto wsm = (float (*)[A_])smem;
            auto part45 = (float (*)[4])(smem + 512);
            auto Psm = (float (*)[A_])(smem + 1536);
            if (tid < A_ * A_) wsm[tid / A_][tid % A_] = argw[n * A_ * A_ + tid];
            __syncthreads();
            const int p0 = idxs[n * IDXW + S_] + 1;
            float pp[45] = {};
            float vals[3][A_];
#pragma unroll
            for (int c = 0; c < 3; ++c) {
                const int d = tid + 256 * c;
                float raw[A_];
#pragma unroll
                for (int k = 0; k < A_; ++k) raw[k] = all_emb[((size_t)(n * L_ + p0 + k)) * D_ + d];
#pragma unroll
                for (int a = 0; a < A_; ++a) {
                    float acc = 0.f;
#pragma unroll
                    for (int k = 0; k < A_; ++k) acc = fmaf(raw[k], wsm[k][a], acc);
                    vals[c][a] = acc;
                    argE[((size_t)(n * A_ + a)) * D_ + d] = acc;
                    argEbf[((size_t)(n * A_ + a)) * D_ + d] = f2bf(acc);
                }
                int p = 0;
#pragma unroll
                for (int a = 0; a < A_; ++a)
#pragma unroll
                    for (int bb = a; bb < A_; ++bb) pp[p++] += vals[c][a] * vals[c][bb];
            }
            const int lane = tid & 63, wv = tid >> 6;
#pragma unroll
            for (int p = 0; p < 45; ++p) {
                float v = pp[p];
                for (int off = 32; off; off >>= 1) v += __shfl_down(v, off, 64);
                if (lane == 0) part45[p][wv] = v;
            }
            __syncthreads();
            if (tid < 45) part45[tid][0] = part45[tid][0] + part45[tid][1] + part45[tid][2] + part45[tid][3];
            __syncthreads();
            if (tid < A_) {
                const int a = tid;
                float v[A_], mx = -1e30f;
#pragma unroll
                for (int bb = 0; bb < A_; ++bb) {
                    const int lo = a < bb ? a : bb, hi = a < bb ? bb : a;
                    v[bb] = part45[lo * (19 - lo) / 2 + hi - lo][0];
                    mx = fmaxf(mx, v[bb]);
                }
                float sm = 0.f;
#pragma unroll
                for (int bb = 0; bb < A_; ++bb) { v[bb] = expf(v[bb] - mx); sm += v[bb]; }
                const float inv = 1.0f / sm;
#pragma unroll
                for (int bb = 0; bb < A_; ++bb) Psm[a][bb] = v[bb] * inv;
            }
            __syncthreads();
#pragma unroll
            for (int c = 0; c < 3; ++c) {
                const int d = tid + 256 * c;
#pragma unroll
                for (int a = 0; a < A_; ++a) {
                    float acc = 0.f;
#pragma unroll
                    for (int bb = 0; bb < A_; ++bb) acc = fmaf(Psm[a][bb], vals[c][bb], acc);
                    u2ubf[((size_t)(n * A_ + a)) * D_ + d] = f2bf(acc);
                }
            }
        }
        __syncthreads();
    }
    gbar(bar);

    // ---------------- phase 2: ent = entmapT@sent (192) + M1 = entmapT@t2t (32) ----------------
    for (int b = blockIdx.x; b < 224; b += G) {
        short (*As)[40] = (short (*)[40])smem;
        short (*Bs)[40] = (short (*)[40])(smem + 10240);
        const int wave = tid >> 6, lane = tid & 63;
        const int row16 = lane & 15, quad = lane >> 4;
        f32x4v acc[2][4] = {};
        if (b < 192) {
            const int n = b / 12, c0 = (b % 12) * 64;
            gemm_body128(entmapT + (size_t)n * S_ * S_, sentT + (size_t)n * D_ * S_,
                         S_, S_, c0, tid, As, Bs, acc);
#pragma unroll
            for (int mi = 0; mi < 2; ++mi)
#pragma unroll
                for (int ni = 0; ni < 4; ++ni) {
                    const int rbase = wave * 32 + mi * 16 + quad * 4;
                    const int col = c0 + ni * 16 + row16;
#pragma unroll
                    for (int t = 0; t < 4; ++t) {
                        const size_t o = ((size_t)(n * S_) + rbase + t) * D_ + col;
                        entf[o] = acc[mi][ni][t];
                        entbf[o] = f2bf(acc[mi][ni][t]);
                    }
                }
        } else {
            const int idx = b - 192;
            const int n = idx >> 1, c0 = (idx & 1) * 64;
            gemm_body128(entmapT + (size_t)n * S_ * S_, t2tT + (size_t)n * S_ * S_,
                         S_, S_, c0, tid, As, Bs, acc);
#pragma unroll
            for (int mi = 0; mi < 2; ++mi)
#pragma unroll
                for (int ni = 0; ni < 4; ++ni) {
                    const int rbase = wave * 32 + mi * 16 + quad * 4;
                    const int col = c0 + ni * 16 + row16;
#pragma unroll
                    for (int t = 0; t < 4; ++t)
                        M1bf[((size_t)(n * S_) + rbase + t) * S_ + col] = f2bf(acc[mi][ni][t]);
                }
        }
        __syncthreads();
    }
    gbar(bar);

    // ---------------- phase 3: Ah2h = M1@sent (192) + w via MFMA (16) ----------------
    for (int b = blockIdx.x; b < 208; b += G) {
        const int wave = tid >> 6, lane = tid & 63;
        const int row16 = lane & 15, quad = lane >> 4;
        if (b < 192) {
            short (*As)[40] = (short (*)[40])smem;
            short (*Bs)[40] = (short (*)[40])(smem + 10240);
            const int n = b / 12, c0 = (b % 12) * 64;
            f32x4v acc[2][4] = {};
            gemm_body128(M1bf + (size_t)n * S_ * S_, sentT + (size_t)n * D_ * S_,
                         S_, S_, c0, tid, As, Bs, acc);
#pragma unroll
            for (int mi = 0; mi < 2; ++mi)
#pragma unroll
                for (int ni = 0; ni < 4; ++ni) {
                    const int rbase = wave * 32 + mi * 16 + quad * 4;
                    const int col = c0 + ni * 16 + row16;
#pragma unroll
                    for (int t = 0; t < 4; ++t)
                        Ah2hbf[((size_t)(n * S_) + rbase + t) * D_ + col] = f2bf(acc[mi][ni][t]);
                }
        } else {
            // t2a via MFMA: C[128][16] = entbf[n](128x768) @ argEbf[n](9x768 padded)^T
            const int n = b - 192;
            const unsigned short* Aent = entbf + (size_t)n * E_ * D_;
            const unsigned short* Barg = argEbf + (size_t)n * A_ * D_;
            f32x4v acc[2] = {};
            for (int k0 = 0; k0 < D_; k0 += 32) {
                bshort8 a[2], bb;
#pragma unroll
                for (int mi = 0; mi < 2; ++mi)
                    a[mi] = *reinterpret_cast<const bshort8*>(Aent + (size_t)(wave * 32 + mi * 16 + row16) * D_ + k0 + quad * 8);
                // rows 9..15 read past argE[n] into adjacent workspace (allocated); cols 9..15 discarded
                bb = *reinterpret_cast<const bshort8*>(Barg + (size_t)row16 * D_ + k0 + quad * 8);
#pragma unroll
                for (int mi = 0; mi < 2; ++mi)
                    acc[mi] = __builtin_amdgcn_mfma_f32_16x16x32_bf16(a[mi], bb, acc[mi], 0, 0, 0);
            }
            if (row16 < A_) {
#pragma unroll
                for (int mi = 0; mi < 2; ++mi)
#pragma unroll
                    for (int t = 0; t < 4; ++t) {
                        const int e = wave * 32 + mi * 16 + quad * 4 + t;
                        const float w = (acc[mi][t] * INV_SQRT_D - 5.0f) * 0.5f;
                        wbuf[((size_t)(n * E_ + e)) * A_ + row16] = w;
                    }
            }
        }
        __syncthreads();
    }
    gbar(bar);

    // ---------------- phase 4: tokA (2048) + argT (144), read wbuf ----------------
    for (int b = blockIdx.x; b < N_ * E_ + N_ * A_; b += G) {
        if (b < N_ * E_) {
            const int n = b >> 7, e = b & 127;
            float* wl = (float*)smem;
            if (tid < A_) wl[tid] = wbuf[(size_t)(n * E_ + e) * A_ + tid];
            __syncthreads();
            const float* ar = argE + (size_t)n * A_ * D_;
#pragma unroll
            for (int c = 0; c < 3; ++c) {
                const int d = tid + 256 * c;
                float s = 0.f;
#pragma unroll
                for (int a = 0; a < A_; ++a) s = fmaf(wl[a], ar[(size_t)a * D_ + d], s);
                tokAbf[((size_t)(n * E_ + e)) * D_ + d] = f2bf(s);
            }
        } else {
            const int idx = b - N_ * E_;
            const int n = idx / A_, a = idx % A_;
            float* wl = (float*)smem;            // E_ floats
            if (tid < E_) wl[tid] = wbuf[(size_t)(n * E_ + tid) * A_ + a];
            __syncthreads();
            const float* eb = entf + (size_t)n * E_ * D_;
#pragma unroll
            for (int c = 0; c < 3; ++c) {
                const int d = tid + 256 * c;
                float acc = 0.f;
                for (int e = 0; e < E_; ++e) acc = fmaf(wl[e], eb[(size_t)e * D_ + d], acc);
                argTbf[((size_t)(n * A_ + a)) * D_ + d] = f2bf(acc);
            }
        }
        __syncthreads();
    }
    gbar(bar);

    // ---------------- phase 5: MLP layer 1, K-split into 3 disjoint partials (648) ----------------
    for (int b = blockIdx.x; b < 648; b += G) {
        short (*As)[40] = (short (*)[40])smem;
        short (*Bs)[40] = (short (*)[40])(smem + 10240);
        const int segblk = b % 54;
        const int c0 = (b / 54) * 64;
        const int seg = segblk % 3;
        const int blk = segblk / 3;
        const bool isPa = blk >= 16;
        const unsigned short* Aseg;
        int woff;
        if (isPa) {
            Aseg = seg == 0 ? argEbf : (seg == 1 ? argTbf : u2ubf);
            woff = seg == 0 ? 1 * D_ : (seg == 1 ? 4 * D_ : 5 * D_);
        } else {
            Aseg = seg == 0 ? entbf : (seg == 1 ? tokAbf : Ah2hbf);
            woff = seg == 0 ? 0 : (seg == 1 ? 2 * D_ : 3 * D_);
        }
        const int M = isPa ? N_ * A_ : N_ * E_;
        const int r0 = (isPa ? blk - 16 : blk) * 128;
        float* C = isPa ? (Pa3 + (size_t)seg * PASZ) : (Pe3 + (size_t)seg * PESZ);
        const int wave = tid >> 6, lane = tid & 63;
        const int row16 = lane & 15, quad = lane >> 4;
        f32x4v acc[2][4] = {};
        for (int kk = 0; kk < D_; kk += 32) {
#pragma unroll
            for (int i = 0; i < 2; ++i) {
                const int idx = tid + 256 * i;
                const int r = idx >> 2, q = idx & 3;
                bshort8 av = {};
                if (r0 + r < M) av = *reinterpret_cast<const bshort8*>(Aseg + (size_t)(r0 + r) * D_ + kk + q * 8);
                *reinterpret_cast<bshort8*>(&As[r][q * 8]) = av;
            }
            {
                const int col = tid >> 2, q = tid & 3;
                *reinterpret_cast<bshort8*>(&Bs[col][q * 8]) =
                    *reinterpret_cast<const bshort8*>(W1t + (size_t)(c0 + col) * W1R + woff + kk + q * 8);
            }
            __syncthreads();
            bshort8 a[2], bb[4];
#pragma unroll
            for (int mi = 0; mi < 2; ++mi)
                a[mi] = *reinterpret_cast<const bshort8*>(&As[wave * 32 + mi * 16 + row16][quad * 8]);
#pragma unroll
            for (int ni = 0; ni < 4; ++ni)
                bb[ni] = *reinterpret_cast<const bshort8*>(&Bs[ni * 16 + row16][quad * 8]);
#pragma unroll
            for (int mi = 0; mi < 2; ++mi)
#pragma unroll
                for (int ni = 0; ni < 4; ++ni)
                    acc[mi][ni] = __builtin_amdgcn_mfma_f32_16x16x32_bf16(a[mi], bb[ni], acc[mi][ni], 0, 0, 0);
            __syncthreads();
        }
#pragma unroll
        for (int mi = 0; mi < 2; ++mi) {
#pragma unroll
            for (int ni = 0; ni < 4; ++ni) {
                const int rbase = r0 + wave * 32 + mi * 16 + quad * 4;
                const int col = c0 + ni * 16 + row16;
#pragma unroll
                for (int t = 0; t < 4; ++t)
                    if (rbase + t < M) C[(size_t)(rbase + t) * H_ + col] = acc[mi][ni][t];
            }
        }
        __syncthreads();
    }
    gbar(bar);

    // ---------------- phase 6: gelu(ΣPe+ΣPa+b1)@W2 + b2, scatter (2048) ----------------
    for (int b = blockIdx.x; b < N_ * E_; b += G) {
        const int n = b >> 7, e = b & 127;
        float* paS = (float*)smem;                 // A_*H_ = 27648B
        float* part = (float*)(smem + 27648);      // A_*4 floats
        float* orow = out + ((size_t)(n * E_ + e)) * RO_;
        if (tid < RO_) orow[tid] = -1000000.0f;
        for (int i = tid; i < A_ * H_; i += 256) {
            const size_t o = (size_t)n * A_ * H_ + i;
            paS[i] = Pa3[o] + Pa3[PASZ + o] + Pa3[2 * PASZ + o];
        }
        __syncthreads();
        const size_t ro = ((size_t)(n * E_ + e)) * H_;
        float acc[A_] = {};
        for (int h = tid; h < H_; h += 256) {
            const float pe = Pe3[ro + h] + Pe3[PESZ + ro + h] + Pe3[2 * PESZ + ro + h] + b1[h];
            const float w2 = W2[h];
#pragma unroll
            for (int a = 0; a < A_; ++a) {
                const float x = pe + paS[a * H_ + h];
                const float g = x * 0.5f * (1.0f + erff(x * 0.70710678118654752f));
                acc[a] = fmaf(g, w2, acc[a]);
            }
        }
        const int lane = tid & 63, wv = tid >> 6;
#pragma unroll
        for (int a = 0; a < A_; ++a)
            for (int off = 32; off; off >>= 1) acc[a] += __shfl_down(acc[a], off, 64);
        if (lane == 0)
            for (int a = 0; a < A_; ++a) part[a * 4 + wv] = acc[a];
        __syncthreads();
        if (tid < A_) {
            const float s = part[tid * 4] + part[tid * 4 + 1] + part[tid * 4 + 2] + part[tid * 4 + 3] + b2[0];
            orow[arg_map[n * A_ + tid]] = s;
        }
        __syncthreads();
    }
}

extern "C" void kernel_launch(void* const* d_in, const int* in_sizes, int n_in,
                              void* d_out, int out_size, void* d_ws, size_t ws_size,
                              hipStream_t stream) {
    const float* all_emb = (const float*)d_in[0];
    const float* attn    = (const float*)d_in[1];
    const float* ent_map = (const float*)d_in[2];
    const float* argw    = (const float*)d_in[3];
    // d_in[4] is_triggers unused (reference dead code)
    const float* W1 = (const float*)d_in[5];
    const float* b1 = (const float*)d_in[6];
    const float* W2 = (const float*)d_in[7];
    const float* b2 = (const float*)d_in[8];
    const int* idxs    = (const int*)d_in[9];
    const int* arg_map = (const int*)d_in[10];
    float* out = (float*)d_out;

    float* ws = (float*)d_ws;
    // fp32 buffers (float offsets)
    float* entf = ws + 0;               // N*E*D           = 1,572,864
    float* Pe3  = ws + 1572864;         // 3*N*E*H         = 4,718,592  -> 6,291,456
    float* argE = ws + 6291456;         // N*A*D           =   110,592  -> 6,402,048
    float* Pa3  = ws + 6402048;         // 3*N*A*H         =   331,776  -> 6,733,824
    float* wbuf = ws + 6733824;         // N*E*A           =    18,432  -> 6,752,256
    // bf16 buffers (offsets in float-slots; sizes = shorts/2)
    short*          W1t     = (short*)(ws + 6752256);           // 768*4608 sh -> 8,521,728
    unsigned short* sentT   = (unsigned short*)(ws + 8521728);  // N*D*S sh    -> 9,308,160
    unsigned short* entmapT = (unsigned short*)(ws + 9308160);  // N*E*S sh    -> 9,439,232
    unsigned short* t2tT    = (unsigned short*)(ws + 9439232);  // N*S*S sh    -> 9,570,304
    unsigned short* M1bf    = (unsigned short*)(ws + 9570304);  // N*E*S sh    -> 9,701,376
    unsigned short* argEbf  = (unsigned short*)(ws + 9701376);  // N*A*D sh    -> 9,756,672
    unsigned short* u2ubf   = (unsigned short*)(ws + 9756672);  // N*A*D sh    -> 9,811,968
    unsigned short* entbf   = (unsigned short*)(ws + 9811968);  // N*E*D sh    -> 10,598,400
    unsigned short* Ah2hbf  = (unsigned short*)(ws + 10598400); // N*E*D sh    -> 11,384,832
    unsigned short* tokAbf  = (unsigned short*)(ws + 11384832); // N*E*D sh    -> 12,171,264
    unsigned short* argTbf  = (unsigned short*)(ws + 12171264); // N*A*D sh    -> 12,226,560
    unsigned*       bar     = (unsigned*)(ws + 12226560);       // 64B barrier state
    // total ≈ 12.23M floats ≈ 48.9 MB

    // grid sized to guaranteed co-residency (hand-rolled grid barrier inside)
    static int bpc = 0;
    if (bpc == 0) {
        int nb = 0;
        if (hipOccupancyMaxActiveBlocksPerMultiprocessor(&nb, mega_k, 256, 0) != hipSuccess || nb < 1) nb = 1;
        if (nb > 4) nb = 4;   // LDS 33.8KB caps at 4/CU anyway
        bpc = nb;
    }
    const int G = bpc * 256;  // 256 CUs on MI355X

    hipMemsetAsync((void*)bar, 0, 64, stream);
    mega_k<<<G, 256, 0, stream>>>(all_emb, attn, ent_map, argw, W1, b1, W2, b2,
                                  idxs, arg_map, out,
                                  entf, Pe3, argE, Pa3, wbuf, W1t,
                                  sentT, entmapT, t2tT, M1bf, argEbf, u2ubf,
                                  entbf, Ah2hbf, tokAbf, argTbf, bar);

    (void)in_sizes; (void)n_in; (void)out_size; (void)ws_size;
}

// Round 5
// 359.053 us; speedup vs baseline: 1.8572x; 1.8572x over previous
//
#include <hip/hip_runtime.h>
#include <math.h>

namespace {
constexpr int N_ = 16, L_ = 256, S_ = 128, E_ = 128, A_ = 9, D_ = 768, H_ = 768, RO_ = 24;
constexpr int IDXW = 130;       // S+2
constexpr int W1R = 6 * D_;     // 4608
constexpr float INV_SQRT_D = 0.03608439182435161f; // 1/sqrt(768)
// stage1 block ranges
constexpr int GB_T2T    = 0;       // 1024 (16 n x 64 s-pairs)
constexpr int GB_W1T    = 1024;    // 864  (72 k-tiles x 12 h-tiles)
constexpr int GB_GATHER = 1888;    // 64   (16 n x 4 row-blocks)
constexpr int GB_ENTMAP = 1952;    // 16
constexpr int GB_ARGU   = 1968;    // 16
constexpr int GB_TOTAL  = 1984;
} // namespace

using bshort8 = __attribute__((ext_vector_type(8))) short;
using f32x4v = __attribute__((ext_vector_type(4))) float;

__device__ __forceinline__ unsigned short f2bf(float f) {
    unsigned u = __builtin_bit_cast(unsigned, f);
    return (unsigned short)((u + 0x7fffu + ((u >> 16) & 1u)) >> 16);
}
__device__ __forceinline__ float bf2f(unsigned short u) {
    return __builtin_bit_cast(float, ((unsigned)u) << 16);
}

// staged 128x64-tile GEMM: acc += A(128xK) @ B(Kx64), B given as BT[col][k]
__device__ __forceinline__ void gemm_tileK(const unsigned short* __restrict__ A, int lda,
                                           const unsigned short* __restrict__ BT, int ldb,
                                           int klen, int c0, int tid,
                                           short (*As)[40], short (*Bs)[40],
                                           f32x4v acc[2][4]) {
    const int wave = tid >> 6, lane = tid & 63;
    const int row16 = lane & 15, quad = lane >> 4;
    for (int k0 = 0; k0 < klen; k0 += 32) {
#pragma unroll
        for (int i = 0; i < 2; ++i) {
            const int idx = tid + 256 * i;
            const int r = idx >> 2, q = idx & 3;
            *reinterpret_cast<bshort8*>(&As[r][q * 8]) =
                *reinterpret_cast<const bshort8*>(A + (size_t)r * lda + k0 + q * 8);
        }
        {
            const int col = tid >> 2, q = tid & 3;
            *reinterpret_cast<bshort8*>(&Bs[col][q * 8]) =
                *reinterpret_cast<const bshort8*>(BT + (size_t)(c0 + col) * ldb + k0 + q * 8);
        }
        __syncthreads();
        bshort8 a[2], b[4];
#pragma unroll
        for (int mi = 0; mi < 2; ++mi)
            a[mi] = *reinterpret_cast<const bshort8*>(&As[wave * 32 + mi * 16 + row16][quad * 8]);
#pragma unroll
        for (int ni = 0; ni < 4; ++ni)
            b[ni] = *reinterpret_cast<const bshort8*>(&Bs[ni * 16 + row16][quad * 8]);
#pragma unroll
        for (int mi = 0; mi < 2; ++mi)
#pragma unroll
            for (int ni = 0; ni < 4; ++ni)
                acc[mi][ni] = __builtin_amdgcn_mfma_f32_16x16x32_bf16(a[mi], b[ni], acc[mi][ni], 0, 0, 0);
        __syncthreads();
    }
}

// ======== L1: input-only transforms (1984 blocks) ========
__global__ __launch_bounds__(256) void stage1_k(const float* __restrict__ all_emb,
                                                const int* __restrict__ idxs,
                                                const float* __restrict__ ent_map,
                                                const float* __restrict__ W1,
                                                const float* __restrict__ argw,
                                                const float* __restrict__ attn,
                                                unsigned short* __restrict__ sentbf,
                                                unsigned short* __restrict__ entmapT,
                                                short* __restrict__ W1t,
                                                unsigned short* __restrict__ t2tbf,
                                                unsigned short* __restrict__ argEbf,
                                                float* __restrict__ Pmat) {
    __shared__ __align__(16) unsigned char smem[33792];
    const int b = blockIdx.x, tid = threadIdx.x;

    if (b < GB_W1T) {
        // ---- t2t: two s-rows per block; row-major t2t[n][s][t] ----
        const int idx = b - GB_T2T;
        const int n = idx >> 6;
        const int half = tid >> 7, t128 = tid & 127;
        const int s = ((idx & 63) << 1) | half;
        const int w = t128 >> 6, lane = tid & 63;
        float* sum2 = (float*)smem;                       // [2][3][2][256]
        float* part = (float*)(smem + 12288);             // 12 floats
        const int is = idxs[n * IDXW + s], it = idxs[n * IDXW + t128];
#pragma unroll
        for (int l = 0; l < 3; ++l) {
            const float* base = attn + ((size_t)((l * N_ + n) * 12 + w * 6)) * (L_ * L_)
                              + (size_t)is * L_ + lane * 4;
            float4 acc = {0.f, 0.f, 0.f, 0.f};
#pragma unroll
            for (int h = 0; h < 6; ++h) {
                const float4 v = *reinterpret_cast<const float4*>(base + (size_t)h * (L_ * L_));
                acc.x += v.x; acc.y += v.y; acc.z += v.z; acc.w += v.w;
            }
            *reinterpret_cast<float4*>(&sum2[(((half * 3 + l) * 2 + w) << 8) + lane * 4]) = acc;
        }
        __syncthreads();
        float m[3];
#pragma unroll
        for (int l = 0; l < 3; ++l) {
            m[l] = (sum2[(((half * 3 + l) * 2 + 0) << 8) + it] +
                    sum2[(((half * 3 + l) * 2 + 1) << 8) + it]) * (1.0f / 12.0f);
            float r = m[l];
#pragma unroll
            for (int off = 32; off; off >>= 1) r += __shfl_xor(r, off, 64);
            if (lane == 0) part[(half * 3 + l) * 2 + w] = r;
        }
        __syncthreads();
        float o = 0.f;
#pragma unroll
        for (int l = 0; l < 3; ++l)
            o += m[l] / (part[(half * 3 + l) * 2 + 0] + part[(half * 3 + l) * 2 + 1] + 1e-9f);
        t2tbf[((size_t)(n * S_ + s)) * S_ + t128] = f2bf(o * (1.0f / 3.0f));
    } else if (b < GB_GATHER) {
        // ---- W1t[h][k] = bf16(W1[k][h]) ----
        const int b2 = b - GB_W1T;
        const int k0 = (b2 % 72) * 64, h0 = (b2 / 72) * 64;
        auto tile = (float (*)[65])smem;
        const int tx = tid & 63, ty = tid >> 6;
#pragma unroll
        for (int i = 0; i < 16; ++i) {
            const int r = ty + i * 4;
            tile[r][tx] = W1[(size_t)(k0 + r) * H_ + h0 + tx];
        }
        __syncthreads();
#pragma unroll
        for (int i = 0; i < 16; ++i) {
            const int r = ty + i * 4;
            W1t[(size_t)(h0 + r) * W1R + k0 + tx] = (short)f2bf(tile[tx][r]);
        }
    } else if (b < GB_ENTMAP) {
        // ---- gather row-major: sentbf[n][s][d] = bf16(all_emb[n][idx[s]][d]) ----
        const int b2 = b - GB_GATHER;
        const int n = b2 >> 2, r0 = (b2 & 3) * 32;
#pragma unroll
        for (int it = 0; it < 24; ++it) {
            const int lin = tid + 256 * it;            // 32 rows x 192 float4
            const int row = lin / 192, dq = (lin % 192) * 4;
            const int grow = idxs[n * IDXW + r0 + row];
            const float4 v = *reinterpret_cast<const float4*>(all_emb + ((size_t)(n * L_ + grow)) * D_ + dq);
            ushort4 u = {f2bf(v.x), f2bf(v.y), f2bf(v.z), f2bf(v.w)};
            *reinterpret_cast<ushort4*>(sentbf + ((size_t)(n * S_) + r0 + row) * D_ + dq) = u;
        }
    } else if (b < GB_ARGU) {
        // ---- entmapT[n][e][s] = bf16(ent_map[n][s][e]) ----
        const int n = b - GB_ENTMAP;
        auto tile = (unsigned short (*)[132])smem;
#pragma unroll
        for (int it = 0; it < 16; ++it) {
            const int lin = tid + 256 * it;
            const int s = lin >> 5, eq = (lin & 31) * 4;
            const float4 v = *reinterpret_cast<const float4*>(ent_map + ((size_t)(n * S_ + s)) * E_ + eq);
            tile[eq + 0][s] = f2bf(v.x); tile[eq + 1][s] = f2bf(v.y);
            tile[eq + 2][s] = f2bf(v.z); tile[eq + 3][s] = f2bf(v.w);
        }
        __syncthreads();
#pragma unroll
        for (int it = 0; it < 16; ++it) {
            const int lin = tid + 256 * it;
            const int e = lin >> 5, s4 = (lin & 31) * 4;
            ushort4 v = {tile[e][s4], tile[e][s4 + 1], tile[e][s4 + 2], tile[e][s4 + 3]};
            *reinterpret_cast<ushort4*>(entmapT + ((size_t)(n * E_) + e) * S_ + s4) = v;
        }
    } else {
        // ---- argU: argE (bf16, padded 16 rows) + softmax P (9x9) ----
        const int n = b - GB_ARGU;
        auto wsm = (float (*)[A_])smem;
        auto part45 = (float (*)[4])(smem + 512);
        auto Psm = (float (*)[A_])(smem + 1536);
        if (tid < A_ * A_) wsm[tid / A_][tid % A_] = argw[n * A_ * A_ + tid];
        // zero pad rows 9..15 of argEbf
        for (int i = tid; i < 7 * D_; i += 256) argEbf[((size_t)(n * 16) + 9) * D_ + i] = 0;
        __syncthreads();
        const int p0 = idxs[n * IDXW + S_] + 1;
        float pp[45] = {};
        float vals[3][A_];
#pragma unroll
        for (int c = 0; c < 3; ++c) {
            const int d = tid + 256 * c;
            float raw[A_];
#pragma unroll
            for (int k = 0; k < A_; ++k) raw[k] = all_emb[((size_t)(n * L_ + p0 + k)) * D_ + d];
#pragma unroll
            for (int a = 0; a < A_; ++a) {
                float acc = 0.f;
#pragma unroll
                for (int k = 0; k < A_; ++k) acc = fmaf(raw[k], wsm[k][a], acc);
                vals[c][a] = acc;
                argEbf[((size_t)(n * 16 + a)) * D_ + d] = f2bf(acc);
            }
            int p = 0;
#pragma unroll
            for (int a = 0; a < A_; ++a)
#pragma unroll
                for (int bb = a; bb < A_; ++bb) pp[p++] += vals[c][a] * vals[c][bb];
        }
        const int lane = tid & 63, wv = tid >> 6;
#pragma unroll
        for (int p = 0; p < 45; ++p) {
            float v = pp[p];
            for (int off = 32; off; off >>= 1) v += __shfl_down(v, off, 64);
            if (lane == 0) part45[p][wv] = v;
        }
        __syncthreads();
        if (tid < 45) part45[tid][0] = part45[tid][0] + part45[tid][1] + part45[tid][2] + part45[tid][3];
        __syncthreads();
        if (tid < A_) {
            const int a = tid;
            float v[A_], mx = -1e30f;
#pragma unroll
            for (int bb = 0; bb < A_; ++bb) {
                const int lo = a < bb ? a : bb, hi = a < bb ? bb : a;
                v[bb] = part45[lo * (19 - lo) / 2 + hi - lo][0];
                mx = fmaxf(mx, v[bb]);
            }
            float sm = 0.f;
#pragma unroll
            for (int bb = 0; bb < A_; ++bb) { v[bb] = expf(v[bb] - mx); sm += v[bb]; }
            const float inv = 1.0f / sm;
#pragma unroll
            for (int bb = 0; bb < A_; ++bb) Psm[a][bb] = v[bb] * inv;
        }
        __syncthreads();
        if (tid < A_ * A_) Pmat[n * 81 + tid] = Psm[tid / A_][tid % A_];
    }
}

// ======== L2: SW_j = sent@W1_j (576) + argEW_j = argE@W1_j (48) + SA = sent@argE^T (16) ========
__global__ __launch_bounds__(256) void l2_k(const unsigned short* __restrict__ sentbf,
                                            const short* __restrict__ W1t,
                                            const unsigned short* __restrict__ argEbf,
                                            unsigned short* __restrict__ SWT,
                                            float* __restrict__ argEW,
                                            unsigned short* __restrict__ SAT) {
    __shared__ __align__(16) short As[128][40];
    __shared__ __align__(16) short Bs[64][40];
    const int bx = blockIdx.x, tid = threadIdx.x;
    const int wave = tid >> 6, lane = tid & 63;
    const int row16 = lane & 15, quad = lane >> 4;
    if (bx < 576) {
        // SW_j: C = sent(128x768) @ W1seg_j -> SWT[j3][n][h][s] bf16
        const int j3 = bx / 192;
        const int jseg = (j3 == 0 ? 0 : (j3 == 1 ? 3 : 4));
        const int rem = bx % 192;
        const int n = rem / 12, c0 = (rem % 12) * 64;
        f32x4v acc[2][4] = {};
        gemm_tileK(sentbf + (size_t)n * S_ * D_, D_,
                   (const unsigned short*)W1t + (size_t)jseg * D_, W1R,
                   D_, c0, tid, As, Bs, acc);
        unsigned short* outb = SWT + ((size_t)(j3 * N_ + n)) * H_ * S_;
#pragma unroll
        for (int mi = 0; mi < 2; ++mi)
#pragma unroll
            for (int ni = 0; ni < 4; ++ni) {
                const int rbase = wave * 32 + mi * 16 + quad * 4;
                const int col = c0 + ni * 16 + row16;
                ushort4 v = {f2bf(acc[mi][ni][0]), f2bf(acc[mi][ni][1]),
                             f2bf(acc[mi][ni][2]), f2bf(acc[mi][ni][3])};
                *reinterpret_cast<ushort4*>(outb + (size_t)col * S_ + rbase) = v;
            }
    } else if (bx < 624) {
        // argEW_j: C = argE(16x768)@W1seg_j -> argEW[j3][n][a][h] fp32 (a<9)
        const int idx = bx - 576;
        const int j3 = idx / 16;
        const int jseg = (j3 == 0 ? 1 : (j3 == 1 ? 2 : 5));
        const int n = idx % 16;
        const unsigned short* Ar = argEbf + (size_t)n * 16 * D_;
        const unsigned short* BT = (const unsigned short*)W1t + (size_t)jseg * D_;
        float* outp = argEW + ((size_t)(j3 * N_ + n)) * A_ * H_;
#pragma unroll
        for (int i = 0; i < 12; ++i) {
            const int col0 = (wave * 12 + i) * 16;
            f32x4v acc = {};
            for (int k0 = 0; k0 < D_; k0 += 32) {
                bshort8 a8 = *reinterpret_cast<const bshort8*>(Ar + (size_t)row16 * D_ + k0 + quad * 8);
                bshort8 b8 = *reinterpret_cast<const bshort8*>(BT + (size_t)(col0 + row16) * W1R + k0 + quad * 8);
                acc = __builtin_amdgcn_mfma_f32_16x16x32_bf16(a8, b8, acc, 0, 0, 0);
            }
#pragma unroll
            for (int t = 0; t < 4; ++t) {
                const int a = quad * 4 + t;
                if (a < A_) outp[(size_t)a * H_ + col0 + row16] = acc[t];
            }
        }
    } else {
        // SA = sent(128x768) @ argE^T -> SAT[n][a][s] bf16
        const int n = bx - 624;
        const unsigned short* Asent = sentbf + (size_t)n * S_ * D_;
        const unsigned short* BT = argEbf + (size_t)n * 16 * D_;
        f32x4v acc[2] = {};
        for (int k0 = 0; k0 < D_; k0 += 32) {
            bshort8 a8[2], b8;
#pragma unroll
            for (int mi = 0; mi < 2; ++mi)
                a8[mi] = *reinterpret_cast<const bshort8*>(Asent + (size_t)(wave * 32 + mi * 16 + row16) * D_ + k0 + quad * 8);
            b8 = *reinterpret_cast<const bshort8*>(BT + (size_t)row16 * D_ + k0 + quad * 8);
#pragma unroll
            for (int mi = 0; mi < 2; ++mi)
                acc[mi] = __builtin_amdgcn_mfma_f32_16x16x32_bf16(a8[mi], b8, acc[mi], 0, 0, 0);
        }
#pragma unroll
        for (int mi = 0; mi < 2; ++mi) {
            const int rbase = wave * 32 + mi * 16 + quad * 4;
            ushort4 v = {f2bf(acc[mi][0]), f2bf(acc[mi][1]), f2bf(acc[mi][2]), f2bf(acc[mi][3])};
            *reinterpret_cast<ushort4*>(SAT + ((size_t)(n * 16) + row16) * S_ + rbase) = v;
        }
    }
}

// ======== L3: T3 = t2t@SW3 (192) + EW4 = entmapT@SW4 (192) + w = f(entmapT@SA) (16) ========
__global__ __launch_bounds__(256) void l3_k(const unsigned short* __restrict__ t2tbf,
                                            const unsigned short* __restrict__ entmapT,
                                            const unsigned short* __restrict__ SWT,
                                            const unsigned short* __restrict__ SAT,
                                            unsigned short* __restrict__ T3T,
                                            unsigned short* __restrict__ EW4T,
                                            float* __restrict__ wfp,
                                            unsigned short* __restrict__ wTbf) {
    __shared__ __align__(16) short As[128][40];
    __shared__ __align__(16) short Bs[64][40];
    const int bx = blockIdx.x, tid = threadIdx.x;
    const int wave = tid >> 6, lane = tid & 63;
    const int row16 = lane & 15, quad = lane >> 4;
    if (bx < 384) {
        // z=0: T3 = t2t @ SW3 -> T3T[n][h][s]; z=1: EW4 = entmapT @ SW4 -> EW4T[n][h][e]
        const int z = bx / 192;
        const int idx = bx % 192;
        const int n = idx / 12, c0 = (idx % 12) * 64;
        const unsigned short* A = (z == 0 ? t2tbf : entmapT) + (size_t)n * S_ * S_;
        const unsigned short* BT = SWT + ((size_t)((z + 1) * N_ + n)) * H_ * S_;
        unsigned short* outb = (z == 0 ? T3T : EW4T) + (size_t)n * H_ * S_;
        f32x4v acc[2][4] = {};
        gemm_tileK(A, S_, BT, S_, S_, c0, tid, As, Bs, acc);
#pragma unroll
        for (int mi = 0; mi < 2; ++mi)
#pragma unroll
            for (int ni = 0; ni < 4; ++ni) {
                const int rbase = wave * 32 + mi * 16 + quad * 4;
                const int col = c0 + ni * 16 + row16;
                ushort4 v = {f2bf(acc[mi][ni][0]), f2bf(acc[mi][ni][1]),
                             f2bf(acc[mi][ni][2]), f2bf(acc[mi][ni][3])};
                *reinterpret_cast<ushort4*>(outb + (size_t)col * S_ + rbase) = v;
            }
    } else {
        // w: t2a = entmapT @ SAT^T(as BT); w = (t2a/sqrtD - 5)/2
        const int n = bx - 384;
        const unsigned short* A = entmapT + (size_t)n * S_ * S_;
        const unsigned short* BT = SAT + (size_t)n * 16 * S_;
        f32x4v acc[2] = {};
        for (int k0 = 0; k0 < S_; k0 += 32) {
            bshort8 a8[2], b8;
#pragma unroll
            for (int mi = 0; mi < 2; ++mi)
                a8[mi] = *reinterpret_cast<const bshort8*>(A + (size_t)(wave * 32 + mi * 16 + row16) * S_ + k0 + quad * 8);
            b8 = *reinterpret_cast<const bshort8*>(BT + (size_t)row16 * S_ + k0 + quad * 8);
#pragma unroll
            for (int mi = 0; mi < 2; ++mi)
                acc[mi] = __builtin_amdgcn_mfma_f32_16x16x32_bf16(a8[mi], b8, acc[mi], 0, 0, 0);
        }
#pragma unroll
        for (int mi = 0; mi < 2; ++mi) {
            const int rbase = wave * 32 + mi * 16 + quad * 4;
            float wv[4];
            ushort4 u;
#pragma unroll
            for (int t = 0; t < 4; ++t) {
                wv[t] = (acc[mi][t] * INV_SQRT_D - 5.0f) * 0.5f;
                if (row16 < A_) wfp[((size_t)(n * E_) + rbase + t) * A_ + row16] = wv[t];
            }
            u.x = f2bf(wv[0]); u.y = f2bf(wv[1]); u.z = f2bf(wv[2]); u.w = f2bf(wv[3]);
            *reinterpret_cast<ushort4*>(wTbf + ((size_t)(n * 16) + row16) * S_ + rbase) = u;
        }
    }
}

// ======== L4: Pe = entmapT@(SW0+T3) + w@argEW2 (192) + Pa assembly (16) ========
__global__ __launch_bounds__(256) void l4_k(const unsigned short* __restrict__ entmapT,
                                            const unsigned short* __restrict__ SWT,
                                            const unsigned short* __restrict__ T3T,
                                            const float* __restrict__ wfp,
                                            const float* __restrict__ argEW,
                                            const unsigned short* __restrict__ wTbf,
                                            const unsigned short* __restrict__ EW4T,
                                            const float* __restrict__ Pmat,
                                            float* __restrict__ Pe, float* __restrict__ Pa) {
    __shared__ __align__(16) unsigned char smem[28416];
    const int bx = blockIdx.x, tid = threadIdx.x;
    const int wave = tid >> 6, lane = tid & 63;
    const int row16 = lane & 15, quad = lane >> 4;
    if (bx < 192) {
        short (*As)[40] = (short (*)[40])smem;             // 10240
        short (*Bs)[40] = (short (*)[40])(smem + 10240);   // 5120
        float* wS = (float*)(smem + 15360);                // 128*9 = 4608B
        float* aW2 = (float*)(smem + 19968);               // 9*64 = 2304B
        const int n = bx / 12, c0 = (bx % 12) * 64;
        for (int i = tid; i < E_ * A_; i += 256) wS[i] = wfp[(size_t)n * E_ * A_ + i];
        for (int i = tid; i < A_ * 64; i += 256) {
            const int a = i >> 6, hc = i & 63;
            aW2[i] = argEW[((size_t)(1 * N_ + n) * A_ + a) * H_ + c0 + hc];
        }
        const unsigned short* A = entmapT + (size_t)n * S_ * S_;
        const unsigned short* B0 = SWT + ((size_t)(0 * N_ + n)) * H_ * S_;
        const unsigned short* B1 = T3T + (size_t)n * H_ * S_;
        f32x4v acc[2][4] = {};
        for (int k0 = 0; k0 < S_; k0 += 32) {
#pragma unroll
            for (int i = 0; i < 2; ++i) {
                const int idx = tid + 256 * i;
                const int r = idx >> 2, q = idx & 3;
                *reinterpret_cast<bshort8*>(&As[r][q * 8]) =
                    *reinterpret_cast<const bshort8*>(A + (size_t)r * S_ + k0 + q * 8);
            }
            {
                const int col = tid >> 2, q = tid & 3;
                const bshort8 u0 = *reinterpret_cast<const bshort8*>(B0 + (size_t)(c0 + col) * S_ + k0 + q * 8);
                const bshort8 u1 = *reinterpret_cast<const bshort8*>(B1 + (size_t)(c0 + col) * S_ + k0 + q * 8);
                bshort8 s;
#pragma unroll
                for (int e8 = 0; e8 < 8; ++e8)
                    s[e8] = (short)f2bf(bf2f((unsigned short)u0[e8]) + bf2f((unsigned short)u1[e8]));
                *reinterpret_cast<bshort8*>(&Bs[col][q * 8]) = s;
            }
            __syncthreads();
            bshort8 a[2], b[4];
#pragma unroll
            for (int mi = 0; mi < 2; ++mi)
                a[mi] = *reinterpret_cast<const bshort8*>(&As[wave * 32 + mi * 16 + row16][quad * 8]);
#pragma unroll
            for (int ni = 0; ni < 4; ++ni)
                b[ni] = *reinterpret_cast<const bshort8*>(&Bs[ni * 16 + row16][quad * 8]);
#pragma unroll
            for (int mi = 0; mi < 2; ++mi)
#pragma unroll
                for (int ni = 0; ni < 4; ++ni)
                    acc[mi][ni] = __builtin_amdgcn_mfma_f32_16x16x32_bf16(a[mi], b[ni], acc[mi][ni], 0, 0, 0);
            __syncthreads();
        }
#pragma unroll
        for (int mi = 0; mi < 2; ++mi)
#pragma unroll
            for (int ni = 0; ni < 4; ++ni) {
                const int rbase = wave * 32 + mi * 16 + quad * 4;
                const int hc = ni * 16 + row16;
#pragma unroll
                for (int t = 0; t < 4; ++t) {
                    const int e = rbase + t;
                    float v = acc[mi][ni][t];
#pragma unroll
                    for (int a = 0; a < A_; ++a) v = fmaf(wS[e * A_ + a], aW2[a * 64 + hc], v);
                    Pe[((size_t)(n * E_) + e) * H_ + c0 + hc] = v;
                }
            }
    } else {
        // Pa[a][h] = (wT @ EW4)[a][h] + argEW1[a][h] + sum_b P[a][b]*argEW5[b][h]
        const int n = bx - 192;
        float* a5 = (float*)smem;                    // 9*768 fp32 = 27648
        float* Pm = (float*)(smem + 27648);          // 81
        for (int i = tid; i < A_ * H_; i += 256) a5[i] = argEW[((size_t)(2 * N_ + n)) * A_ * H_ + i];
        if (tid < A_ * A_) Pm[tid] = Pmat[n * 81 + tid];
        __syncthreads();
        const unsigned short* A = wTbf + (size_t)n * 16 * S_;
        const unsigned short* BT = EW4T + (size_t)n * H_ * S_;
        const float* a1 = argEW + ((size_t)(0 * N_ + n)) * A_ * H_;
#pragma unroll
        for (int i = 0; i < 12; ++i) {
            const int col0 = (wave * 12 + i) * 16;
            f32x4v acc = {};
            for (int k0 = 0; k0 < S_; k0 += 32) {
                bshort8 a8 = *reinterpret_cast<const bshort8*>(A + (size_t)row16 * S_ + k0 + quad * 8);
                bshort8 b8 = *reinterpret_cast<const bshort8*>(BT + (size_t)(col0 + row16) * S_ + k0 + quad * 8);
                acc = __builtin_amdgcn_mfma_f32_16x16x32_bf16(a8, b8, acc, 0, 0, 0);
            }
            const int h = col0 + row16;
#pragma unroll
            for (int t = 0; t < 4; ++t) {
                const int a = quad * 4 + t;
                if (a < A_) {
                    float v = acc[t] + a1[(size_t)a * H_ + h];
#pragma unroll
                    for (int bb = 0; bb < A_; ++bb) v = fmaf(Pm[a * A_ + bb], a5[bb * H_ + h], v);
                    Pa[((size_t)(n * A_) + a) * H_ + h] = v;
                }
            }
        }
    }
}

// ======== L5: gelu(Pe+Pa+b1)@W2 + b2, scatter ========
__global__ __launch_bounds__(256) void score_k(const float* __restrict__ Pe, const float* __restrict__ Pa,
                                               const float* __restrict__ b1, const float* __restrict__ W2,
                                               const float* __restrict__ b2, const int* __restrict__ arg_map,
                                               float* __restrict__ out) {
    const int n = blockIdx.x >> 7, e = blockIdx.x & 127;
    const int tid = threadIdx.x;
    __shared__ float paS[A_ * H_];
    __shared__ float part[A_][4];
    float* orow = out + ((size_t)(n * E_ + e)) * RO_;
    if (tid < RO_) orow[tid] = -1000000.0f;
    for (int i = tid; i < A_ * H_; i += 256) paS[i] = Pa[(size_t)n * A_ * H_ + i];
    __syncthreads();
    const size_t ro = ((size_t)(n * E_ + e)) * H_;
    float acc[A_] = {};
    for (int h = tid; h < H_; h += 256) {
        const float pe = Pe[ro + h] + b1[h];
        const float w2 = W2[h];
#pragma unroll
        for (int a = 0; a < A_; ++a) {
            const float x = pe + paS[a * H_ + h];
            const float g = x * 0.5f * (1.0f + erff(x * 0.70710678118654752f));
            acc[a] = fmaf(g, w2, acc[a]);
        }
    }
    const int lane = tid & 63, wv = tid >> 6;
#pragma unroll
    for (int a = 0; a < A_; ++a)
        for (int off = 32; off; off >>= 1) acc[a] += __shfl_down(acc[a], off, 64);
    if (lane == 0)
        for (int a = 0; a < A_; ++a) part[a][wv] = acc[a];
    __syncthreads();
    if (tid < A_) {
        const float s = part[tid][0] + part[tid][1] + part[tid][2] + part[tid][3] + b2[0];
        orow[arg_map[n * A_ + tid]] = s;
    }
}

extern "C" void kernel_launch(void* const* d_in, const int* in_sizes, int n_in,
                              void* d_out, int out_size, void* d_ws, size_t ws_size,
                              hipStream_t stream) {
    const float* all_emb = (const float*)d_in[0];
    const float* attn    = (const float*)d_in[1];
    const float* ent_map = (const float*)d_in[2];
    const float* argw    = (const float*)d_in[3];
    // d_in[4] is_triggers unused (reference dead code)
    const float* W1 = (const float*)d_in[5];
    const float* b1 = (const float*)d_in[6];
    const float* W2 = (const float*)d_in[7];
    const float* b2 = (const float*)d_in[8];
    const int* idxs    = (const int*)d_in[9];
    const int* arg_map = (const int*)d_in[10];
    float* out = (float*)d_out;

    float* ws = (float*)d_ws;
    // fp32 buffers (float offsets)
    float* Pe    = ws + 0;               // N*E*H            = 1,572,864
    float* Pa    = ws + 1572864;         // N*A*H            =   110,592 -> 1,683,456
    float* wfp   = ws + 1683456;         // N*E*A            =    18,432 -> 1,701,888
    float* argEW = ws + 1701888;         // 3*N*A*H          =   331,776 -> 2,033,664
    float* Pmat  = ws + 2033664;         // N*81             =     1,296 -> 2,034,960
    // bf16 buffers (offsets in float-slots; sizes in shorts)
    short*          W1t     = (short*)(ws + 2034960);          // 768*4608    -> 3,804,432
    unsigned short* sentbf  = (unsigned short*)(ws + 3804432); // N*S*D       -> 4,590,864
    unsigned short* entmapT = (unsigned short*)(ws + 4590864); // N*E*S       -> 4,721,936
    unsigned short* t2tbf   = (unsigned short*)(ws + 4721936); // N*S*S       -> 4,853,008
    unsigned short* argEbf  = (unsigned short*)(ws + 4853008); // N*16*D      -> 4,951,312
    unsigned short* SWT     = (unsigned short*)(ws + 4951312); // 3*N*H*S     -> 7,310,608
    unsigned short* SAT     = (unsigned short*)(ws + 7310608); // N*16*S      -> 7,326,992
    unsigned short* T3T     = (unsigned short*)(ws + 7326992); // N*H*S       -> 8,113,424
    unsigned short* EW4T    = (unsigned short*)(ws + 8113424); // N*H*S       -> 8,899,856
    unsigned short* wTbf    = (unsigned short*)(ws + 8899856); // N*16*S      -> 8,916,240
    // total ≈ 8.92M floats ≈ 35.7 MB

    // L1: transforms (t2t, W1t, gather, entmapT, argE+P)
    stage1_k<<<GB_TOTAL, 256, 0, stream>>>(all_emb, idxs, ent_map, W1, argw, attn,
                                           sentbf, entmapT, W1t, t2tbf, argEbf, Pmat);
    // L2: SW_j (j=0,3,4), argEW_j (j=1,2,5), SA
    l2_k<<<640, 256, 0, stream>>>(sentbf, W1t, argEbf, SWT, argEW, SAT);
    // L3: T3 = t2t@SW3, EW4 = entmapT@SW4, w = f(entmapT@SA)
    l3_k<<<400, 256, 0, stream>>>(t2tbf, entmapT, SWT, SAT, T3T, EW4T, wfp, wTbf);
    // L4: Pe = entmapT@(SW0+T3) + w@argEW2 ; Pa = wT@EW4 + argEW1 + P@argEW5
    l4_k<<<208, 256, 0, stream>>>(entmapT, SWT, T3T, wfp, argEW, wTbf, EW4T, Pmat, Pe, Pa);
    // L5: score
    score_k<<<N_ * E_, 256, 0, stream>>>(Pe, Pa, b1, W2, b2, arg_map, out);

    (void)in_sizes; (void)n_in; (void)out_size; (void)ws_size;
}

// Round 6
// 319.761 us; speedup vs baseline: 2.0854x; 1.1229x over previous
//
#include <hip/hip_runtime.h>
#include <math.h>

namespace {
constexpr int N_ = 16, L_ = 256, S_ = 128, E_ = 128, A_ = 9, D_ = 768, H_ = 768, RO_ = 24;
constexpr int IDXW = 130;       // S+2
constexpr int W1R = 6 * D_;     // 4608
constexpr float INV_SQRT_D = 0.03608439182435161f; // 1/sqrt(768)
constexpr int PESZ = 2048 * 768;   // one Pe partial
constexpr int PASZ = 144 * 768;    // one Pa partial
// stage1 block ranges (longest work first); union LDS = 16.9 KB (was 33.8 -> 2x occupancy)
constexpr int GB_T2T    = 0;       // 1024 (16 n x 64 s-pairs)
constexpr int GB_W1T    = 1024;    // 864  (72 k-tiles x 12 h-tiles)
constexpr int GB_GATHER = 1888;    // 192  (16 n x 12 d-tiles)
constexpr int GB_ENTMAP = 2080;    // 32   (16 n x 2 e-halves)
constexpr int GB_ARGU   = 2112;    // 16
constexpr int GB_TOTAL  = 2128;
} // namespace

using bshort8 = __attribute__((ext_vector_type(8))) short;
using f32x4v = __attribute__((ext_vector_type(4))) float;

__device__ __forceinline__ unsigned short f2bf(float f) {
    unsigned u = __builtin_bit_cast(unsigned, f);
    return (unsigned short)((u + 0x7fffu + ((u >> 16) & 1u)) >> 16);
}

// A&S 7.1.26 erf, |err| <= 1.5e-7 (<< bf16 noise floor); ~2x cheaper than libm erff
__device__ __forceinline__ float erf_fast(float x) {
    const float ax = fabsf(x);
    const float t = 1.0f / fmaf(0.3275911f, ax, 1.0f);
    float p = fmaf(1.061405429f, t, -1.453152027f);
    p = fmaf(p, t, 1.421413741f);
    p = fmaf(p, t, -0.284496736f);
    p = fmaf(p, t, 0.254829592f);
    p = p * t;
    const float r = 1.0f - p * __expf(-ax * ax);
    return copysignf(r, x);
}

// shared 128x64-tile K=128 GEMM body: acc += A(128x128) @ B(128x64 from BT[col][k])
__device__ __forceinline__ void gemm_body128(const unsigned short* __restrict__ A,
                                             const unsigned short* __restrict__ BT,
                                             int lda, int ldb, int c0, int tid,
                                             short (*As)[40], short (*Bs)[40],
                                             f32x4v acc[2][4]) {
    const int wave = tid >> 6, lane = tid & 63;
    const int row16 = lane & 15, quad = lane >> 4;
    for (int k0 = 0; k0 < S_; k0 += 32) {
#pragma unroll
        for (int i = 0; i < 2; ++i) {
            const int idx = tid + 256 * i;
            const int r = idx >> 2, q = idx & 3;
            *reinterpret_cast<bshort8*>(&As[r][q * 8]) =
                *reinterpret_cast<const bshort8*>(A + (size_t)r * lda + k0 + q * 8);
        }
        {
            const int col = tid >> 2, q = tid & 3;
            *reinterpret_cast<bshort8*>(&Bs[col][q * 8]) =
                *reinterpret_cast<const bshort8*>(BT + (size_t)(c0 + col) * ldb + k0 + q * 8);
        }
        __syncthreads();
        bshort8 a[2], b[4];
#pragma unroll
        for (int mi = 0; mi < 2; ++mi)
            a[mi] = *reinterpret_cast<const bshort8*>(&As[wave * 32 + mi * 16 + row16][quad * 8]);
#pragma unroll
        for (int ni = 0; ni < 4; ++ni)
            b[ni] = *reinterpret_cast<const bshort8*>(&Bs[ni * 16 + row16][quad * 8]);
#pragma unroll
        for (int mi = 0; mi < 2; ++mi)
#pragma unroll
            for (int ni = 0; ni < 4; ++ni)
                acc[mi][ni] = __builtin_amdgcn_mfma_f32_16x16x32_bf16(a[mi], b[ni], acc[mi][ni], 0, 0, 0);
        __syncthreads();
    }
}

// ======== stage 1 mega-kernel: all input-only transforms; union LDS 16.9 KB ========
__global__ __launch_bounds__(256) void stage1_k(const float* __restrict__ all_emb,
                                                const int* __restrict__ idxs,
                                                const float* __restrict__ ent_map,
                                                const float* __restrict__ W1,
                                                const float* __restrict__ argw,
                                                const float* __restrict__ attn,
                                                unsigned short* __restrict__ sentT,
                                                unsigned short* __restrict__ entmapT,
                                                short* __restrict__ W1t,
                                                unsigned short* __restrict__ t2tT,
                                                float* __restrict__ argE,
                                                unsigned short* __restrict__ argEbf,
                                                unsigned short* __restrict__ u2ubf) {
    __shared__ __align__(16) unsigned char smem[16896];
    const int b = blockIdx.x, tid = threadIdx.x;

    if (b < GB_W1T) {
        // ---- t2t: two s-rows per block; output TRANSPOSED t2tT[n][t][s] ----
        const int idx = b - GB_T2T;
        const int n = idx >> 6;
        const int half = tid >> 7, t128 = tid & 127;
        const int s0 = (idx & 63) << 1;
        const int s = s0 | half;
        const int w = t128 >> 6, lane = tid & 63;
        float* sum2 = (float*)smem;                       // [2][3][2][256] = 12288B
        float* part = (float*)(smem + 12288);             // 12 floats
        unsigned short* tileT = (unsigned short*)(smem + 12544); // [128][2] = 512B
        const int is = idxs[n * IDXW + s], it = idxs[n * IDXW + t128];
#pragma unroll
        for (int l = 0; l < 3; ++l) {
            const float* base = attn + ((size_t)((l * N_ + n) * 12 + w * 6)) * (L_ * L_)
                              + (size_t)is * L_ + lane * 4;
            float4 acc = {0.f, 0.f, 0.f, 0.f};
#pragma unroll
            for (int h = 0; h < 6; ++h) {
                const float4 v = *reinterpret_cast<const float4*>(base + (size_t)h * (L_ * L_));
                acc.x += v.x; acc.y += v.y; acc.z += v.z; acc.w += v.w;
            }
            *reinterpret_cast<float4*>(&sum2[(((half * 3 + l) * 2 + w) << 8) + lane * 4]) = acc;
        }
        __syncthreads();
        float m[3];
#pragma unroll
        for (int l = 0; l < 3; ++l) {
            m[l] = (sum2[(((half * 3 + l) * 2 + 0) << 8) + it] +
                    sum2[(((half * 3 + l) * 2 + 1) << 8) + it]) * (1.0f / 12.0f);
            float r = m[l];
#pragma unroll
            for (int off = 32; off; off >>= 1) r += __shfl_xor(r, off, 64);
            if (lane == 0) part[(half * 3 + l) * 2 + w] = r;
        }
        __syncthreads();
        float o = 0.f;
#pragma unroll
        for (int l = 0; l < 3; ++l)
            o += m[l] / (part[(half * 3 + l) * 2 + 0] + part[(half * 3 + l) * 2 + 1] + 1e-9f);
        tileT[t128 * 2 + half] = f2bf(o * (1.0f / 3.0f));
        __syncthreads();
        if (tid < 128) {
            const unsigned int v = ((const unsigned int*)tileT)[tid];
            *reinterpret_cast<unsigned int*>(t2tT + ((size_t)(n * S_) + tid) * S_ + s0) = v;
        }
    } else if (b < GB_GATHER) {
        // ---- W1t[h][k] = bf16(W1[k][h]) ----
        const int b2 = b - GB_W1T;
        const int k0 = (b2 % 72) * 64, h0 = (b2 / 72) * 64;
        auto tile = (float (*)[65])smem;             // [64][65] = 16640B
        const int tx = tid & 63, ty = tid >> 6;
#pragma unroll
        for (int i = 0; i < 16; ++i) {
            const int r = ty + i * 4;
            tile[r][tx] = W1[(size_t)(k0 + r) * H_ + h0 + tx];
        }
        __syncthreads();
#pragma unroll
        for (int i = 0; i < 16; ++i) {
            const int r = ty + i * 4;
            W1t[(size_t)(h0 + r) * W1R + k0 + tx] = (short)f2bf(tile[tx][r]);
        }
    } else if (b < GB_ENTMAP) {
        // ---- gatherT: sentT[n][d][s] = bf16(all_emb[n][idx[s]][d]) ----
        const int b2 = b - GB_GATHER;
        const int n = b2 / 12, d0 = (b2 % 12) * 64;
        auto tile = (unsigned short (*)[132])smem;   // [64][132] = 16896B
#pragma unroll
        for (int it = 0; it < 8; ++it) {
            const int lin = tid + 256 * it;
            const int s = lin >> 4, dq = (lin & 15) * 4;
            const int row = idxs[n * IDXW + s];
            const float4 v = *reinterpret_cast<const float4*>(all_emb + ((size_t)(n * L_ + row)) * D_ + d0 + dq);
            tile[dq + 0][s] = f2bf(v.x); tile[dq + 1][s] = f2bf(v.y);
            tile[dq + 2][s] = f2bf(v.z); tile[dq + 3][s] = f2bf(v.w);
        }
        __syncthreads();
#pragma unroll
        for (int it = 0; it < 8; ++it) {
            const int lin = tid + 256 * it;
            const int d = lin >> 5, s4 = (lin & 31) * 4;
            ushort4 v = {tile[d][s4], tile[d][s4 + 1], tile[d][s4 + 2], tile[d][s4 + 3]};
            *reinterpret_cast<ushort4*>(sentT + ((size_t)(n * D_) + d0 + d) * S_ + s4) = v;
        }
    } else if (b < GB_ARGU) {
        // ---- entmapT[n][e0+e][s] = bf16(ent_map[n][s][e0+e]), 64-e chunks ----
        const int idx = b - GB_ENTMAP;
        const int n = idx >> 1, e0 = (idx & 1) * 64;
        auto tile = (unsigned short (*)[132])smem;   // [64][132]
#pragma unroll
        for (int it = 0; it < 8; ++it) {
            const int lin = tid + 256 * it;          // 128 s x 16 e-quads
            const int s = lin >> 4, eq = (lin & 15) * 4;
            const float4 v = *reinterpret_cast<const float4*>(ent_map + ((size_t)(n * S_ + s)) * E_ + e0 + eq);
            tile[eq + 0][s] = f2bf(v.x); tile[eq + 1][s] = f2bf(v.y);
            tile[eq + 2][s] = f2bf(v.z); tile[eq + 3][s] = f2bf(v.w);
        }
        __syncthreads();
#pragma unroll
        for (int it = 0; it < 8; ++it) {
            const int lin = tid + 256 * it;          // 64 e x 32 s-quads
            const int e = lin >> 5, s4 = (lin & 31) * 4;
            ushort4 v = {tile[e][s4], tile[e][s4 + 1], tile[e][s4 + 2], tile[e][s4 + 3]};
            *reinterpret_cast<ushort4*>(entmapT + ((size_t)(n * E_) + e0 + e) * S_ + s4) = v;
        }
    } else {
        // ---- arg_u2u: arg_emb + a2a softmax + u2u ----
        const int n = b - GB_ARGU;
        auto wsm = (float (*)[A_])smem;
        auto part45 = (float (*)[4])(smem + 512);
        auto Psm = (float (*)[A_])(smem + 1536);
        if (tid < A_ * A_) wsm[tid / A_][tid % A_] = argw[n * A_ * A_ + tid];
        __syncthreads();
        const int p0 = idxs[n * IDXW + S_] + 1;
        float pp[45] = {};
        float vals[3][A_];
#pragma unroll
        for (int c = 0; c < 3; ++c) {
            const int d = tid + 256 * c;
            float raw[A_];
#pragma unroll
            for (int k = 0; k < A_; ++k) raw[k] = all_emb[((size_t)(n * L_ + p0 + k)) * D_ + d];
#pragma unroll
            for (int a = 0; a < A_; ++a) {
                float acc = 0.f;
#pragma unroll
                for (int k = 0; k < A_; ++k) acc = fmaf(raw[k], wsm[k][a], acc);
                vals[c][a] = acc;
                argE[((size_t)(n * A_ + a)) * D_ + d] = acc;
                argEbf[((size_t)(n * A_ + a)) * D_ + d] = f2bf(acc);
            }
            int p = 0;
#pragma unroll
            for (int a = 0; a < A_; ++a)
#pragma unroll
                for (int bb = a; bb < A_; ++bb) pp[p++] += vals[c][a] * vals[c][bb];
        }
        const int lane = tid & 63, wv = tid >> 6;
#pragma unroll
        for (int p = 0; p < 45; ++p) {
            float v = pp[p];
            for (int off = 32; off; off >>= 1) v += __shfl_down(v, off, 64);
            if (lane == 0) part45[p][wv] = v;
        }
        __syncthreads();
        if (tid < 45) part45[tid][0] = part45[tid][0] + part45[tid][1] + part45[tid][2] + part45[tid][3];
        __syncthreads();
        if (tid < A_) {
            const int a = tid;
            float v[A_], mx = -1e30f;
#pragma unroll
            for (int bb = 0; bb < A_; ++bb) {
                const int lo = a < bb ? a : bb, hi = a < bb ? bb : a;
                v[bb] = part45[lo * (19 - lo) / 2 + hi - lo][0];
                mx = fmaxf(mx, v[bb]);
            }
            float sm = 0.f;
#pragma unroll
            for (int bb = 0; bb < A_; ++bb) { v[bb] = expf(v[bb] - mx); sm += v[bb]; }
            const float inv = 1.0f / sm;
#pragma unroll
            for (int bb = 0; bb < A_; ++bb) Psm[a][bb] = v[bb] * inv;
        }
        __syncthreads();
#pragma unroll
        for (int c = 0; c < 3; ++c) {
            const int d = tid + 256 * c;
#pragma unroll
            for (int a = 0; a < A_; ++a) {
                float acc = 0.f;
#pragma unroll
                for (int bb = 0; bb < A_; ++bb) acc = fmaf(Psm[a][bb], vals[c][bb], acc);
                u2ubf[((size_t)(n * A_ + a)) * D_ + d] = f2bf(acc);
            }
        }
    }
}

// ======== stage 2: ent = entmapT@sent (192) + M1 = entmapT@t2t (32) ========
__global__ __launch_bounds__(256) void gemm_pair_k(const unsigned short* __restrict__ entmapT,
                                                   const unsigned short* __restrict__ sentT,
                                                   const unsigned short* __restrict__ t2tT,
                                                   float* __restrict__ entf,
                                                   unsigned short* __restrict__ entbf,
                                                   unsigned short* __restrict__ M1bf) {
    __shared__ __align__(16) short As[128][40];
    __shared__ __align__(16) short Bs[64][40];
    const int bx = blockIdx.x, tid = threadIdx.x;
    const int wave = tid >> 6, lane = tid & 63;
    const int row16 = lane & 15, quad = lane >> 4;
    f32x4v acc[2][4] = {};
    if (bx < 192) {
        const int n = bx / 12, c0 = (bx % 12) * 64;
        gemm_body128(entmapT + (size_t)n * S_ * S_, sentT + (size_t)n * D_ * S_,
                     S_, S_, c0, tid, As, Bs, acc);
#pragma unroll
        for (int mi = 0; mi < 2; ++mi)
#pragma unroll
            for (int ni = 0; ni < 4; ++ni) {
                const int rbase = wave * 32 + mi * 16 + quad * 4;
                const int col = c0 + ni * 16 + row16;
#pragma unroll
                for (int t = 0; t < 4; ++t) {
                    const size_t o = ((size_t)(n * S_) + rbase + t) * D_ + col;
                    entf[o] = acc[mi][ni][t];
                    entbf[o] = f2bf(acc[mi][ni][t]);
                }
            }
    } else {
        const int idx = bx - 192;                 // 0..31
        const int n = idx >> 1, c0 = (idx & 1) * 64;
        gemm_body128(entmapT + (size_t)n * S_ * S_, t2tT + (size_t)n * S_ * S_,
                     S_, S_, c0, tid, As, Bs, acc);
#pragma unroll
        for (int mi = 0; mi < 2; ++mi)
#pragma unroll
            for (int ni = 0; ni < 4; ++ni) {
                const int rbase = wave * 32 + mi * 16 + quad * 4;
                const int col = c0 + ni * 16 + row16;
#pragma unroll
                for (int t = 0; t < 4; ++t)
                    M1bf[((size_t)(n * S_) + rbase + t) * S_ + col] = f2bf(acc[mi][ni][t]);
            }
    }
}

// ======== stage 3: Ah2h = M1@sent (192) + w via MFMA (16) ========
__global__ __launch_bounds__(256) void gemm2_k(const unsigned short* __restrict__ M1bf,
                                               const unsigned short* __restrict__ sentT,
                                               const unsigned short* __restrict__ entbf,
                                               const unsigned short* __restrict__ argEbf,
                                               unsigned short* __restrict__ Ah2hbf,
                                               float* __restrict__ wbuf) {
    const int bx = blockIdx.x, tid = threadIdx.x;
    const int wave = tid >> 6, lane = tid & 63;
    const int row16 = lane & 15, quad = lane >> 4;
    if (bx < 192) {
        __shared__ __align__(16) short As[128][40];
        __shared__ __align__(16) short Bs[64][40];
        const int n = bx / 12, c0 = (bx % 12) * 64;
        f32x4v acc[2][4] = {};
        gemm_body128(M1bf + (size_t)n * S_ * S_, sentT + (size_t)n * D_ * S_,
                     S_, S_, c0, tid, As, Bs, acc);
#pragma unroll
        for (int mi = 0; mi < 2; ++mi)
#pragma unroll
            for (int ni = 0; ni < 4; ++ni) {
                const int rbase = wave * 32 + mi * 16 + quad * 4;
                const int col = c0 + ni * 16 + row16;
#pragma unroll
                for (int t = 0; t < 4; ++t)
                    Ah2hbf[((size_t)(n * S_) + rbase + t) * D_ + col] = f2bf(acc[mi][ni][t]);
            }
    } else {
        // t2a via MFMA: C[128][16] = entbf[n](128x768) @ argEbf[n](9x768 padded)^T
        // then w = (C/sqrt(D) - 5)/2 -> wbuf[n][e][a]
        const int n = bx - 192;
        const unsigned short* Aent = entbf + (size_t)n * E_ * D_;
        const unsigned short* Barg = argEbf + (size_t)n * A_ * D_;
        f32x4v acc[2] = {};
        for (int k0 = 0; k0 < D_; k0 += 32) {
            bshort8 a[2], bb;
#pragma unroll
            for (int mi = 0; mi < 2; ++mi)
                a[mi] = *reinterpret_cast<const bshort8*>(Aent + (size_t)(wave * 32 + mi * 16 + row16) * D_ + k0 + quad * 8);
            // rows 9..15 read past argE[n] into adjacent workspace (allocated); cols 9..15 discarded
            bb = *reinterpret_cast<const bshort8*>(Barg + (size_t)row16 * D_ + k0 + quad * 8);
#pragma unroll
            for (int mi = 0; mi < 2; ++mi)
                acc[mi] = __builtin_amdgcn_mfma_f32_16x16x32_bf16(a[mi], bb, acc[mi], 0, 0, 0);
        }
        if (row16 < A_) {
#pragma unroll
            for (int mi = 0; mi < 2; ++mi)
#pragma unroll
                for (int t = 0; t < 4; ++t) {
                    const int e = wave * 32 + mi * 16 + quad * 4 + t;
                    const float w = (acc[mi][t] * INV_SQRT_D - 5.0f) * 0.5f;
                    wbuf[((size_t)(n * E_ + e)) * A_ + row16] = w;
                }
        }
    }
}

// ======== stage 4: tokA (2048) + argT (144), both read wbuf ========
__global__ __launch_bounds__(256) void post_k(const float* __restrict__ wbuf,
                                              const float* __restrict__ argE,
                                              const float* __restrict__ entf,
                                              unsigned short* __restrict__ tokAbf,
                                              unsigned short* __restrict__ argTbf) {
    const int b = blockIdx.x, tid = threadIdx.x;
    if (b < N_ * E_) {
        // tokA[n,e,:] = sum_a w[n,e,a]*argE[n,a,:]
        const int n = b >> 7, e = b & 127;
        __shared__ float wl[A_];
        if (tid < A_) wl[tid] = wbuf[(size_t)(n * E_ + e) * A_ + tid];
        __syncthreads();
        const float* ar = argE + (size_t)n * A_ * D_;
#pragma unroll
        for (int c = 0; c < 3; ++c) {
            const int d = tid + 256 * c;
            float s = 0.f;
#pragma unroll
            for (int a = 0; a < A_; ++a) s = fmaf(wl[a], ar[(size_t)a * D_ + d], s);
            tokAbf[((size_t)(n * E_ + e)) * D_ + d] = f2bf(s);
        }
    } else {
        // argT[n,a,:] = sum_e w[n,e,a]*ent[n,e,:]
        const int idx = b - N_ * E_;
        const int n = idx / A_, a = idx % A_;
        __shared__ float wl[E_];
        if (tid < E_) wl[tid] = wbuf[(size_t)(n * E_ + tid) * A_ + a];
        __syncthreads();
        const float* eb = entf + (size_t)n * E_ * D_;
#pragma unroll
        for (int c = 0; c < 3; ++c) {
            const int d = tid + 256 * c;
            float acc = 0.f;
            for (int e = 0; e < E_; ++e) acc = fmaf(wl[e], eb[(size_t)e * D_ + d], acc);
            argTbf[((size_t)(n * A_ + a)) * D_ + d] = f2bf(acc);
        }
    }
}

// ======== stage 5: MLP layer 1, K-split into 3 disjoint partial buffers (no atomics) ========
__global__ __launch_bounds__(256) void mfma_mlp_k(const unsigned short* __restrict__ e0,
                                                  const unsigned short* __restrict__ e1,
                                                  const unsigned short* __restrict__ e2,
                                                  const unsigned short* __restrict__ a0,
                                                  const unsigned short* __restrict__ a1,
                                                  const unsigned short* __restrict__ a2,
                                                  const short* __restrict__ W1t,
                                                  float* __restrict__ Pe3, float* __restrict__ Pa3) {
    __shared__ __align__(16) short As[128][40];
    __shared__ __align__(16) short Bs[64][40];
    const int bx = blockIdx.x;          // 0..53
    const int seg = bx % 3;
    const int blk = bx / 3;             // 0..17 (16 Pe row-blocks + 2 Pa row-blocks)
    const bool isPa = blk >= 16;
    const unsigned short* Aseg;
    int woff;
    if (isPa) {
        Aseg = seg == 0 ? a0 : (seg == 1 ? a1 : a2);
        woff = seg == 0 ? 1 * D_ : (seg == 1 ? 4 * D_ : 5 * D_);
    } else {
        Aseg = seg == 0 ? e0 : (seg == 1 ? e1 : e2);
        woff = seg == 0 ? 0 : (seg == 1 ? 2 * D_ : 3 * D_);
    }
    const int M = isPa ? N_ * A_ : N_ * E_;
    const int r0 = (isPa ? blk - 16 : blk) * 128;
    float* C = isPa ? (Pa3 + (size_t)seg * PASZ) : (Pe3 + (size_t)seg * PESZ);
    const int c0 = blockIdx.y * 64;
    const int tid = threadIdx.x;
    const int wave = tid >> 6, lane = tid & 63;
    const int row16 = lane & 15, quad = lane >> 4;
    f32x4v acc[2][4] = {};
    for (int kk = 0; kk < D_; kk += 32) {
#pragma unroll
        for (int i = 0; i < 2; ++i) {
            const int idx = tid + 256 * i;
            const int r = idx >> 2, q = idx & 3;
            bshort8 av = {};
            if (r0 + r < M) av = *reinterpret_cast<const bshort8*>(Aseg + (size_t)(r0 + r) * D_ + kk + q * 8);
            *reinterpret_cast<bshort8*>(&As[r][q * 8]) = av;
        }
        {
            const int col = tid >> 2, q = tid & 3;
            *reinterpret_cast<bshort8*>(&Bs[col][q * 8]) =
                *reinterpret_cast<const bshort8*>(W1t + (size_t)(c0 + col) * W1R + woff + kk + q * 8);
        }
        __syncthreads();
        bshort8 a[2], b[4];
#pragma unroll
        for (int mi = 0; mi < 2; ++mi)
            a[mi] = *reinterpret_cast<const bshort8*>(&As[wave * 32 + mi * 16 + row16][quad * 8]);
#pragma unroll
        for (int ni = 0; ni < 4; ++ni)
            b[ni] = *reinterpret_cast<const bshort8*>(&Bs[ni * 16 + row16][quad * 8]);
#pragma unroll
        for (int mi = 0; mi < 2; ++mi)
#pragma unroll
            for (int ni = 0; ni < 4; ++ni)
                acc[mi][ni] = __builtin_amdgcn_mfma_f32_16x16x32_bf16(a[mi], b[ni], acc[mi][ni], 0, 0, 0);
        __syncthreads();
    }
#pragma unroll
    for (int mi = 0; mi < 2; ++mi) {
#pragma unroll
        for (int ni = 0; ni < 4; ++ni) {
            const int rbase = r0 + wave * 32 + mi * 16 + quad * 4;
            const int col = c0 + ni * 16 + row16;
#pragma unroll
            for (int t = 0; t < 4; ++t)
                if (rbase + t < M) C[(size_t)(rbase + t) * H_ + col] = acc[mi][ni][t];
        }
    }
}

// ======== stage 6: gelu(Pe0+Pe1+Pe2+Pa+b1)@W2 + b2, scatter ========
__global__ __launch_bounds__(256) void score_k(const float* __restrict__ Pe3, const float* __restrict__ Pa3,
                                               const float* __restrict__ b1, const float* __restrict__ W2,
                                               const float* __restrict__ b2, const int* __restrict__ arg_map,
                                               float* __restrict__ out) {
    const int n = blockIdx.x >> 7, e = blockIdx.x & 127;
    const int tid = threadIdx.x;
    __shared__ float paS[A_ * H_];
    __shared__ float part[A_][4];
    float* orow = out + ((size_t)(n * E_ + e)) * RO_;
    if (tid < RO_) orow[tid] = -1000000.0f;
    for (int i = tid; i < A_ * H_; i += 256) {
        const size_t o = (size_t)n * A_ * H_ + i;
        paS[i] = Pa3[o] + Pa3[PASZ + o] + Pa3[2 * PASZ + o];
    }
    __syncthreads();
    const size_t ro = ((size_t)(n * E_ + e)) * H_;
    float acc[A_] = {};
    for (int h = tid; h < H_; h += 256) {
        const float pe = Pe3[ro + h] + Pe3[PESZ + ro + h] + Pe3[2 * PESZ + ro + h] + b1[h];
        const float w2 = W2[h];
#pragma unroll
        for (int a = 0; a < A_; ++a) {
            const float x = pe + paS[a * H_ + h];
            const float g = x * 0.5f * (1.0f + erf_fast(x * 0.70710678118654752f));
            acc[a] = fmaf(g, w2, acc[a]);
        }
    }
    const int lane = tid & 63, wv = tid >> 6;
#pragma unroll
    for (int a = 0; a < A_; ++a)
        for (int off = 32; off; off >>= 1) acc[a] += __shfl_down(acc[a], off, 64);
    if (lane == 0)
        for (int a = 0; a < A_; ++a) part[a][wv] = acc[a];
    __syncthreads();
    if (tid < A_) {
        const float s = part[tid][0] + part[tid][1] + part[tid][2] + part[tid][3] + b2[0];
        orow[arg_map[n * A_ + tid]] = s;
    }
}

extern "C" void kernel_launch(void* const* d_in, const int* in_sizes, int n_in,
                              void* d_out, int out_size, void* d_ws, size_t ws_size,
                              hipStream_t stream) {
    const float* all_emb = (const float*)d_in[0];
    const float* attn    = (const float*)d_in[1];
    const float* ent_map = (const float*)d_in[2];
    const float* argw    = (const float*)d_in[3];
    // d_in[4] is_triggers unused (reference dead code)
    const float* W1 = (const float*)d_in[5];
    const float* b1 = (const float*)d_in[6];
    const float* W2 = (const float*)d_in[7];
    const float* b2 = (const float*)d_in[8];
    const int* idxs    = (const int*)d_in[9];
    const int* arg_map = (const int*)d_in[10];
    float* out = (float*)d_out;

    float* ws = (float*)d_ws;
    // fp32 buffers (float offsets)
    float* entf = ws + 0;               // N*E*D           = 1,572,864
    float* Pe3  = ws + 1572864;         // 3*N*E*H         = 4,718,592  -> 6,291,456
    float* argE = ws + 6291456;         // N*A*D           =   110,592  -> 6,402,048
    float* wbuf = ws + 6402048;         // N*E*A           =    18,432  -> 6,420,480
    float* Pa3  = ws + 6420480;         // 3*N*A*H         =   331,776  -> 6,752,256
    // bf16 buffers (offsets in float-slots; sizes = shorts/2)
    short*          W1t     = (short*)(ws + 6752256);           // 768*4608 sh -> 8,521,728
    unsigned short* sentT   = (unsigned short*)(ws + 8521728);  // N*D*S sh    -> 9,308,160
    unsigned short* entmapT = (unsigned short*)(ws + 9308160);  // N*E*S sh    -> 9,439,232
    unsigned short* t2tT    = (unsigned short*)(ws + 9439232);  // N*S*S sh    -> 9,570,304
    unsigned short* M1bf    = (unsigned short*)(ws + 9570304);  // N*E*S sh    -> 9,701,376
    unsigned short* argEbf  = (unsigned short*)(ws + 9701376);  // N*A*D sh    -> 9,756,672
    unsigned short* u2ubf   = (unsigned short*)(ws + 9756672);  // N*A*D sh    -> 9,811,968 (pads argEbf overrun)
    unsigned short* entbf   = (unsigned short*)(ws + 9811968);  // N*E*D sh    -> 10,598,400
    unsigned short* Ah2hbf  = (unsigned short*)(ws + 10598400); // N*E*D sh    -> 11,384,832
    unsigned short* tokAbf  = (unsigned short*)(ws + 11384832); // N*E*D sh    -> 12,171,264
    unsigned short* argTbf  = (unsigned short*)(ws + 12171264); // N*A*D sh    -> 12,226,560
    // total ≈ 12.23M floats ≈ 48.9 MB

    // L1: all input-only transforms (2128 blocks, 16.9 KB LDS -> ~2x occupancy vs R2)
    stage1_k<<<GB_TOTAL, 256, 0, stream>>>(all_emb, idxs, ent_map, W1, argw, attn,
                                           sentT, entmapT, W1t, t2tT, argE, argEbf, u2ubf);

    // L2: ent = entmapT@sent (192) + M1 = entmapT@t2t (32)
    gemm_pair_k<<<224, 256, 0, stream>>>(entmapT, sentT, t2tT, entf, entbf, M1bf);

    // L3: Ah2h = M1@sent (192) + w via MFMA (16)
    gemm2_k<<<208, 256, 0, stream>>>(M1bf, sentT, entbf, argEbf, Ah2hbf, wbuf);

    // L4: tokA + argT (both consume wbuf)
    post_k<<<N_ * E_ + N_ * A_, 256, 0, stream>>>(wbuf, argE, entf, tokAbf, argTbf);

    // L5: MLP layer 1, K-split by segment into disjoint partials (648 blocks, no atomics)
    // W1 row blocks: [ent 0 | argE 768 | tokA 1536 | Ah2h 2304 | argT 3072 | u2u 3840]
    mfma_mlp_k<<<dim3(54, H_ / 64), 256, 0, stream>>>(entbf, tokAbf, Ah2hbf, argEbf, argTbf, u2ubf, W1t, Pe3, Pa3);

    // L6: gelu + W2 + scatter (sums the 3 partials on read)
    score_k<<<N_ * E_, 256, 0, stream>>>(Pe3, Pa3, b1, W2, b2, arg_map, out);

    (void)in_sizes; (void)n_in; (void)out_size; (void)ws_size;
}